// Round 14
// baseline (405.739 us; speedup 1.0000x reference)
//
#include <hip/hip_runtime.h>
#include <hip/hip_fp16.h>
#include <math.h>

// Problem constants
#define Bb 32
#define Nn 1024
#define DIMc 512
#define Hh 8
#define DHd 64
#define GK 512          // K for both projection GEMMs

typedef __attribute__((ext_vector_type(8))) short short8;     // 16B of 16-bit elems
typedef __attribute__((ext_vector_type(8))) _Float16 half8;   // MFMA f16 A/B frag
typedef __attribute__((ext_vector_type(2))) __fp16 fp16x2;    // cvt_pkrtz result
typedef __attribute__((ext_vector_type(4))) float floatx4;    // MFMA 16x16 acc

#define MFMA16 __builtin_amdgcn_mfma_f32_16x16x32_f16

#if __has_builtin(__builtin_amdgcn_exp2f)
#define EXP2(x) __builtin_amdgcn_exp2f(x)
#else
#define EXP2(x) __expf((x) * 0.6931471805599453f)
#endif

__device__ __forceinline__ unsigned short f16_bits(float f) {
    return __half_as_ushort(__float2half(f));   // RTN
}
// pack 2 fp32 -> 2 fp16 (RTZ) in one dword
__device__ __forceinline__ int cvt_pk_f16(float a, float b) {
    fp16x2 r = __builtin_amdgcn_cvt_pkrtz(a, b);
    return __builtin_bit_cast(int, r);
}

// ---------------------------------------------------------------------------
// Prep 1: transpose fp32 weight [K][N] -> single fp16 [N][K].
// ---------------------------------------------------------------------------
__global__ __launch_bounds__(256) void transpose_half_kernel(
    const float* __restrict__ src, int K, int N,
    unsigned short* __restrict__ dh)
{
    __shared__ float T[32][33];
    const int tid = threadIdx.x;
    const int c = tid & 31, r0 = tid >> 5;
    const int nb = blockIdx.x * 32, kb = blockIdx.y * 32;
    #pragma unroll
    for (int i = 0; i < 4; ++i)
        T[r0 + i * 8][c] = src[(size_t)(kb + r0 + i * 8) * N + nb + c];
    __syncthreads();
    #pragma unroll
    for (int i = 0; i < 4; ++i) {
        int n = r0 + i * 8;
        dh[(size_t)(nb + n) * K + kb + c] = f16_bits(T[c][n]);
    }
}

// ---------------------------------------------------------------------------
// Prep 2: decay fp32 -> fp16, PRE-SCALED by 2^-8 (no-max softmax headroom;
// cancels via inv = 256/sum(p) in the attn epilogue).
// ---------------------------------------------------------------------------
__global__ __launch_bounds__(256) void decay_to_half_kernel(
    const float* __restrict__ D, unsigned short* __restrict__ D16)
{
    size_t i = ((size_t)blockIdx.x * 256 + threadIdx.x) * 4;
    float4 v = *(const float4*)(D + i);
    ushort4 o;
    o.x = f16_bits(v.x * 0.00390625f);
    o.y = f16_bits(v.y * 0.00390625f);
    o.z = f16_bits(v.z * 0.00390625f);
    o.w = f16_bits(v.w * 0.00390625f);
    *(ushort4*)(D16 + i) = o;
}

// ---------------------------------------------------------------------------
// Prep 3: X fp32 -> single fp16 (RTN). Xf aliases AOf (dead until attn).
// ---------------------------------------------------------------------------
__global__ __launch_bounds__(256) void x_to_half_kernel(
    const float* __restrict__ X, unsigned short* __restrict__ Xf)
{
    size_t i = ((size_t)blockIdx.x * 256 + threadIdx.x) * 8;
    float4 a = *(const float4*)(X + i);
    float4 b = *(const float4*)(X + i + 4);
    float f[8] = {a.x, a.y, a.z, a.w, b.x, b.y, b.z, b.w};
    short8 o;
    #pragma unroll
    for (int e = 0; e < 8; ++e) o[e] = (short)f16_bits(f[e]);
    *(short8*)(Xf + i) = o;
}

// ---------------------------------------------------------------------------
// GEMM1 (fp16 single-term): qkv = x @ W_qkv
// R14: NO LDS STAGING, NO MAIN-LOOP BARRIERS. Each MFMA fragment is a
// per-lane 16B global load (operands k-contiguous, L2-resident — FETCH
// already ~24 MB): frag(row = base + t*16 + l16, k = k0 + quad*8).
// 2-deep register pipeline (cur/nxt, static indexing); waves run fully
// asynchronously; TLP (~12 waves/CU) + ILP hide L2 latency.
// Final prefetch overshoots <=568B into the next workspace array (allocated,
// discarded). V-transpose keeps a dedicated LDS bounce (epilogue only).
// XCD-chunked swizzle unchanged.
// ---------------------------------------------------------------------------
__global__ __launch_bounds__(256) void gemm_qkv_mfma(
    const unsigned short* __restrict__ Xf, const unsigned short* __restrict__ Wf,
    unsigned short* __restrict__ Qf, unsigned short* __restrict__ Kf,
    unsigned short* __restrict__ Vt)
{
    __shared__ unsigned short bounce[128][136];   // V-transpose (epilogue only)

    const int tid  = threadIdx.x;
    const int w    = tid >> 6;
    const int lane = tid & 63;
    const int quad = lane >> 4;
    const int l16  = lane & 15;
    // XCD-chunked swizzle: nwg = 3072 = 8 * 384; n-fastest within m-panel
    const int lb = blockIdx.x;
    const int wg = (lb & 7) * 384 + (lb >> 3);
    const int n0 = (wg % 12) * 128;
    const int m0 = (wg / 12) * 128;
    const int wm = w >> 1, wn = w & 1;

    floatx4 acc[4][4];
    #pragma unroll
    for (int im = 0; im < 4; ++im)
        #pragma unroll
        for (int in = 0; in < 4; ++in)
            acc[im][in] = (floatx4){0.f, 0.f, 0.f, 0.f};

    // per-lane fragment base pointers (k-contiguous rows)
    const unsigned short* ap = Xf + (size_t)(m0 + wm * 64 + l16) * GK + quad * 8;
    const unsigned short* bp = Wf + (size_t)(n0 + wn * 64 + l16) * GK + quad * 8;

    half8 aC[4], bC[4], aN[4], bN[4];
    #pragma unroll
    for (int t = 0; t < 4; ++t) {
        aC[t] = *(const half8*)(ap + (size_t)t * 16 * GK);
        bC[t] = *(const half8*)(bp + (size_t)t * 16 * GK);
    }
    for (int k0 = 0; k0 < GK; k0 += 64) {
        #pragma unroll
        for (int t = 0; t < 4; ++t) {
            aN[t] = *(const half8*)(ap + (size_t)t * 16 * GK + k0 + 32);
            bN[t] = *(const half8*)(bp + (size_t)t * 16 * GK + k0 + 32);
        }
        #pragma unroll
        for (int im = 0; im < 4; ++im)
            #pragma unroll
            for (int in = 0; in < 4; ++in)
                acc[im][in] = MFMA16(aC[im], bC[in], acc[im][in], 0, 0, 0);
        #pragma unroll
        for (int t = 0; t < 4; ++t) {   // last iter: k0+64==GK -> garbage-safe
            aC[t] = *(const half8*)(ap + (size_t)t * 16 * GK + k0 + 64);
            bC[t] = *(const half8*)(bp + (size_t)t * 16 * GK + k0 + 64);
        }
        #pragma unroll
        for (int im = 0; im < 4; ++im)
            #pragma unroll
            for (int in = 0; in < 4; ++in)
                acc[im][in] = MFMA16(aN[im], bN[in], acc[im][in], 0, 0, 0);
    }

    // ---- epilogue ----
    const int which = n0 >> 9;       // 0=q 1=k 2=v (128-tiles never straddle)
    const int b    = m0 >> 10;
    const int tokb = m0 & 1023;
    if (which < 2) {
        unsigned short* OUT = which ? Kf : Qf;
        // Q: fold SCALE * log2(e) = 0.125 * 1.4426950408889634
        const float sc = which ? 1.0f : 0.18033688011112042f;
        #pragma unroll
        for (int im = 0; im < 4; ++im) {
            const int tok = tokb + wm * 64 + im * 16 + quad * 4;
            #pragma unroll
            for (int in = 0; in < 4; ++in) {
                const int ncol = n0 + wn * 64 + in * 16 + l16;
                const int h = (ncol & 511) >> 6, d = ncol & 63;
                const size_t base = ((size_t)(b * Hh + h) * Nn + tok) * DHd + d;
                #pragma unroll
                for (int r = 0; r < 4; ++r)
                    OUT[base + (size_t)r * DHd] = f16_bits(acc[im][in][r] * sc);
            }
        }
    } else {
        // V: fp16 + transpose through LDS bounce -> Vt [bh][64][1024]
        #pragma unroll
        for (int im = 0; im < 4; ++im)
            #pragma unroll
            for (int in = 0; in < 4; ++in)
                #pragma unroll
                for (int r = 0; r < 4; ++r)
                    bounce[wm * 64 + im * 16 + quad * 4 + r][wn * 64 + in * 16 + l16] =
                        f16_bits(acc[im][in][r]);
        __syncthreads();
        const int c = tid >> 1, tq = (tid & 1) * 64;
        const int h = ((n0 + c) & 511) >> 6, d = c & 63;
        unsigned short* vbase = Vt + ((size_t)(b * Hh + h) * DHd + d) * Nn + tokb;
        #pragma unroll
        for (int uu = 0; uu < 8; ++uu) {
            short8 v8;
            #pragma unroll
            for (int e = 0; e < 8; ++e)
                v8[e] = (short)bounce[tq + uu * 8 + e][c];
            *(short8*)&vbase[tq + uu * 8] = v8;
        }
    }
}

// ---------------------------------------------------------------------------
// MFMA flash attention (R12 skeleton, unchanged): LDS double-buffer with one
// barrier per tile, 2x Q-rows per wave, no-max softmax, packed-fp16 decay,
// decay-sharing grid remap.
// ---------------------------------------------------------------------------
__global__ __launch_bounds__(256) void attn_mfma_kernel(
    const unsigned short* __restrict__ Qf, const unsigned short* __restrict__ Kf,
    const unsigned short* __restrict__ Vt, const unsigned short* __restrict__ D16,
    unsigned short* __restrict__ AOf)
{
    __shared__ unsigned short Kfs[2][32][72];   // [buf][permuted j][d]
    __shared__ unsigned short Vts[2][64][40];   // [buf][d][j]

    const int tid  = threadIdx.x;
    const int wave = tid >> 6;
    const int lane = tid & 63;
    const int quad = lane >> 4;
    const int l16  = lane & 15;
    const int lb   = blockIdx.x;                 // [0,2048)
    const int xcd  = lb & 7;
    const int r_   = lb >> 3;                    // [0,256)
    const int h    = r_ >> 5;
    const int rem  = r_ & 31;
    const int i0   = (rem >> 2) << 7;            // 8 x 128-row tiles
    const int b    = xcd * 4 + (rem & 3);
    const int bh   = b * 8 + h;
    const int iw   = i0 + wave * 32;             // this wave: rows iw..iw+31

    const size_t qoffA = ((size_t)bh * Nn + iw + l16) * DHd + quad * 8;
    const size_t qoffB = qoffA + (size_t)16 * DHd;
    const half8 qA0 = *(const half8*)(Qf + qoffA);
    const half8 qA1 = *(const half8*)(Qf + qoffA + 32);
    const half8 qB0 = *(const half8*)(Qf + qoffB);
    const half8 qB1 = *(const half8*)(Qf + qoffB + 32);

    floatx4 oA[4], oB[4];
    #pragma unroll
    for (int nt = 0; nt < 4; ++nt) {
        oA[nt] = (floatx4){0.f, 0.f, 0.f, 0.f};
        oB[nt] = (floatx4){0.f, 0.f, 0.f, 0.f};
    }
    float lA = 0.f, lB = 0.f;    // per-lane partial denominators

    const int sj  = tid >> 3, sc2 = (tid & 7) * 8;       // K tile: 32 x 64
    const int prow = ((sj >> 2) & 1) * 16 + ((sj >> 3) << 2) + (sj & 3);
    const int vd  = tid >> 2, vj8 = (tid & 3) * 8;       // Vt tile: 64 x 32
    const unsigned short* DpA = D16 + ((size_t)h * Nn + iw + l16) * Nn + quad * 8;
    const unsigned short* DpB = DpA + (size_t)16 * Nn;

    const unsigned short* kpf = Kf + (size_t)bh * Nn * DHd + (size_t)sj * DHd + sc2;
    const unsigned short* vpv = Vt + (size_t)bh * DHd * Nn + (size_t)vd * Nn + vj8;

    // prologue: tile 0 -> buf0
    short8 pk_f = *(const short8*)kpf; kpf += 32 * DHd;
    short8 pk_v = *(const short8*)vpv; vpv += 32;
    *(short8*)&Kfs[0][prow][sc2] = pk_f;
    *(short8*)&Vts[0][vd][vj8]   = pk_v;
    __syncthreads();

    int cur = 0;
    for (int j0 = 0; j0 < Nn; j0 += 32) {
        // issue next-tile loads (final iter overshoots into adjacent workspace)
        pk_f = *(const short8*)kpf; kpf += 32 * DHd;
        pk_v = *(const short8*)vpv; vpv += 32;
        const short8 dcA = *(const short8*)(DpA + j0);   // 8 fp16 decay*2^-8
        const short8 dcB = *(const short8*)(DpB + j0);

        // QK^T swapped for both q-groups
        floatx4 sA[2], sB[2];
        #pragma unroll
        for (int nh = 0; nh < 2; ++nh) {
            const int kr = nh * 16 + l16;
            half8 kf0 = *(const half8*)&Kfs[cur][kr][quad * 8];
            half8 kf1 = *(const half8*)&Kfs[cur][kr][32 + quad * 8];
            floatx4 a = (floatx4){0.f, 0.f, 0.f, 0.f};
            a = MFMA16(kf0, qA0, a, 0, 0, 0);
            a = MFMA16(kf1, qA1, a, 0, 0, 0);
            sA[nh] = a;
            floatx4 c = (floatx4){0.f, 0.f, 0.f, 0.f};
            c = MFMA16(kf0, qB0, c, 0, 0, 0);
            c = MFMA16(kf1, qB1, c, 0, 0, 0);
            sB[nh] = c;
        }

        // no-max softmax: raw exp2
        float pA[8], pB[8];
        #pragma unroll
        for (int e = 0; e < 4; ++e) {
            pA[e]     = EXP2(sA[0][e]);
            pA[4 + e] = EXP2(sA[1][e]);
            pB[e]     = EXP2(sB[0][e]);
            pB[4 + e] = EXP2(sB[1][e]);
        }
        lA += ((pA[0] + pA[1]) + (pA[2] + pA[3])) + ((pA[4] + pA[5]) + (pA[6] + pA[7]));
        lB += ((pB[0] + pB[1]) + (pB[2] + pB[3])) + ((pB[4] + pB[5]) + (pB[6] + pB[7]));

        // P * (decay*2^-8) -> fp16 A-fragments via packed fp16 multiply
        union { int i4[4]; half8 v8; } pfA, pfB;
        const int* dA = (const int*)&dcA;
        const int* dB = (const int*)&dcB;
        #pragma unroll
        for (int e = 0; e < 4; ++e) {
            fp16x2 pa = __builtin_bit_cast(fp16x2, cvt_pk_f16(pA[2 * e], pA[2 * e + 1]));
            fp16x2 da = __builtin_bit_cast(fp16x2, dA[e]);
            pfA.i4[e] = __builtin_bit_cast(int, pa * da);   // v_pk_mul_f16
            fp16x2 pb = __builtin_bit_cast(fp16x2, cvt_pk_f16(pB[2 * e], pB[2 * e + 1]));
            fp16x2 db = __builtin_bit_cast(fp16x2, dB[e]);
            pfB.i4[e] = __builtin_bit_cast(int, pb * db);
        }
        #pragma unroll
        for (int nt = 0; nt < 4; ++nt) {
            half8 vf = *(const half8*)&Vts[cur][nt * 16 + l16][quad * 8];
            oA[nt] = MFMA16(pfA.v8, vf, oA[nt], 0, 0, 0);
            oB[nt] = MFMA16(pfB.v8, vf, oB[nt], 0, 0, 0);
        }

        // write next tile into the other buffer; single barrier per tile
        *(short8*)&Kfs[cur ^ 1][prow][sc2] = pk_f;
        *(short8*)&Vts[cur ^ 1][vd][vj8]   = pk_v;
        __syncthreads();
        cur ^= 1;
    }

    // reduce per-lane partial denominators across quads (once)
    float lsA = lA;
    lsA += __shfl_xor(lsA, 16);
    lsA += __shfl_xor(lsA, 32);
    float lsB = lB;
    lsB += __shfl_xor(lsB, 16);
    lsB += __shfl_xor(lsB, 32);
    const float invA = 256.f / lsA;     // 2^8 cancels the decay pre-scale
    const float invB = 256.f / lsB;
    float irA[4], irB[4];
    #pragma unroll
    for (int r = 0; r < 4; ++r) {
        irA[r] = __shfl(invA, quad * 4 + r);
        irB[r] = __shfl(invB, quad * 4 + r);
    }
    const size_t aobA = ((size_t)b * Nn + iw) * DIMc + h * DHd;
    const size_t aobB = aobA + (size_t)16 * DIMc;
    #pragma unroll
    for (int nt = 0; nt < 4; ++nt)
        #pragma unroll
        for (int r = 0; r < 4; ++r) {
            const size_t ro = (size_t)(quad * 4 + r) * DIMc + nt * 16 + l16;
            AOf[aobA + ro] = f16_bits(oA[nt][r] * irA[r]);
            AOf[aobB + ro] = f16_bits(oB[nt][r] * irB[r]);
        }
}

// ---------------------------------------------------------------------------
// GEMM2 (fp16 single-term): out = AO @ W_out + b_out
// R14: no LDS, no barriers — direct-from-L2 fragment loads, 2-deep register
// pipeline. XCD-chunked swizzle (nwg = 1024).
// ---------------------------------------------------------------------------
__global__ __launch_bounds__(256) void gemm_out_mfma(
    const unsigned short* __restrict__ Af, const unsigned short* __restrict__ Wf,
    const float* __restrict__ bias, float* __restrict__ C)
{
    const int tid  = threadIdx.x;
    const int w    = tid >> 6;
    const int lane = tid & 63;
    const int quad = lane >> 4;
    const int l16  = lane & 15;
    const int lb = blockIdx.x;
    const int wg = (lb & 7) * 128 + (lb >> 3);
    const int n0 = (wg & 3) * 128;
    const int m0 = (wg >> 2) * 128;
    const int wm = w >> 1, wn = w & 1;

    floatx4 acc[4][4];
    #pragma unroll
    for (int im = 0; im < 4; ++im)
        #pragma unroll
        for (int in = 0; in < 4; ++in)
            acc[im][in] = (floatx4){0.f, 0.f, 0.f, 0.f};

    const unsigned short* ap = Af + (size_t)(m0 + wm * 64 + l16) * GK + quad * 8;
    const unsigned short* bp = Wf + (size_t)(n0 + wn * 64 + l16) * GK + quad * 8;

    half8 aC[4], bC[4], aN[4], bN[4];
    #pragma unroll
    for (int t = 0; t < 4; ++t) {
        aC[t] = *(const half8*)(ap + (size_t)t * 16 * GK);
        bC[t] = *(const half8*)(bp + (size_t)t * 16 * GK);
    }
    for (int k0 = 0; k0 < GK; k0 += 64) {
        #pragma unroll
        for (int t = 0; t < 4; ++t) {
            aN[t] = *(const half8*)(ap + (size_t)t * 16 * GK + k0 + 32);
            bN[t] = *(const half8*)(bp + (size_t)t * 16 * GK + k0 + 32);
        }
        #pragma unroll
        for (int im = 0; im < 4; ++im)
            #pragma unroll
            for (int in = 0; in < 4; ++in)
                acc[im][in] = MFMA16(aC[im], bC[in], acc[im][in], 0, 0, 0);
        #pragma unroll
        for (int t = 0; t < 4; ++t) {   // last iter: k0+64==GK -> garbage-safe
            aC[t] = *(const half8*)(ap + (size_t)t * 16 * GK + k0 + 64);
            bC[t] = *(const half8*)(bp + (size_t)t * 16 * GK + k0 + 64);
        }
        #pragma unroll
        for (int im = 0; im < 4; ++im)
            #pragma unroll
            for (int in = 0; in < 4; ++in)
                acc[im][in] = MFMA16(aN[im], bN[in], acc[im][in], 0, 0, 0);
    }

    float biasv[4];
    #pragma unroll
    for (int in = 0; in < 4; ++in) biasv[in] = bias[n0 + wn * 64 + in * 16 + l16];
    #pragma unroll
    for (int im = 0; im < 4; ++im)
        #pragma unroll
        for (int in = 0; in < 4; ++in) {
            const int mrow = m0 + wm * 64 + im * 16 + quad * 4;
            const int ncol = n0 + wn * 64 + in * 16 + l16;
            #pragma unroll
            for (int r = 0; r < 4; ++r)
                C[(size_t)(mrow + r) * DIMc + ncol] = acc[im][in][r] + biasv[in];
        }
}

// ---------------------------------------------------------------------------
extern "C" void kernel_launch(void* const* d_in, const int* in_sizes, int n_in,
                              void* d_out, int out_size, void* d_ws, size_t ws_size,
                              hipStream_t stream)
{
    const float* x     = (const float*)d_in[0];
    const float* Wqkv  = (const float*)d_in[1];
    const float* Wout  = (const float*)d_in[2];
    const float* bout  = (const float*)d_in[3];
    const float* decay = (const float*)d_in[4];

    const size_t E = (size_t)32768 * 512;   // 16,777,216
    unsigned short* p = (unsigned short*)d_ws;
    unsigned short* Qf  = p; p += E;
    unsigned short* Kf  = p; p += E;        // attn prefetch overshoot -> Vt (ok)
    unsigned short* Vt  = p; p += E;        // attn prefetch overshoot -> AOf (ok)
    unsigned short* AOf = p; p += E;        // gemm prefetch overshoot -> Wq (ok)
    unsigned short* Wq  = p; p += 786432;   // overshoot -> Wo (ok)
    unsigned short* Wo  = p; p += 262144;   // overshoot -> D16 (ok)
    unsigned short* D16 = p;               // 8,388,608 halves
    // total: ~148 MiB. Xf ALIASES AOf (dead until attn writes AO).
    unsigned short* Xf = AOf;

    transpose_half_kernel<<<dim3(48, 16), 256, 0, stream>>>(Wqkv, 512, 1536, Wq);
    transpose_half_kernel<<<dim3(16, 16), 256, 0, stream>>>(Wout, 512, 512, Wo);
    decay_to_half_kernel<<<dim3(8192), 256, 0, stream>>>(decay, D16);
    x_to_half_kernel<<<dim3(8192), 256, 0, stream>>>(x, Xf);
    gemm_qkv_mfma<<<dim3(3072), 256, 0, stream>>>(Xf, Wq, Qf, Kf, Vt);
    attn_mfma_kernel<<<dim3(2048), 256, 0, stream>>>(Qf, Kf, Vt, D16, AOf);
    gemm_out_mfma<<<dim3(1024), 256, 0, stream>>>(AOf, Wo, bout, (float*)d_out);
}

// Round 15
// 288.221 us; speedup vs baseline: 1.4077x; 1.4077x over previous
//
#include <hip/hip_runtime.h>
#include <hip/hip_fp16.h>
#include <math.h>

// Problem constants
#define Bb 32
#define Nn 1024
#define DIMc 512
#define Hh 8
#define DHd 64
#define GK 512          // K for both projection GEMMs

typedef __attribute__((ext_vector_type(8))) short short8;     // 16B of 16-bit elems
typedef __attribute__((ext_vector_type(8))) _Float16 half8;   // MFMA f16 A/B frag
typedef __attribute__((ext_vector_type(2))) __fp16 fp16x2;    // cvt_pkrtz result
typedef __attribute__((ext_vector_type(4))) float floatx4;    // MFMA 16x16 acc

#define MFMA16 __builtin_amdgcn_mfma_f32_16x16x32_f16

#if __has_builtin(__builtin_amdgcn_exp2f)
#define EXP2(x) __builtin_amdgcn_exp2f(x)
#else
#define EXP2(x) __expf((x) * 0.6931471805599453f)
#endif

__device__ __forceinline__ unsigned short f16_bits(float f) {
    return __half_as_ushort(__float2half(f));   // RTN
}
// pack 2 fp32 -> 2 fp16 (RTZ) in one dword
__device__ __forceinline__ int cvt_pk_f16(float a, float b) {
    fp16x2 r = __builtin_amdgcn_cvt_pkrtz(a, b);
    return __builtin_bit_cast(int, r);
}

// async global->LDS, 16 bytes per lane; LDS dest = wave-uniform base + lane*16
__device__ __forceinline__ void gload_lds16(const unsigned short* g, unsigned short* l) {
    __builtin_amdgcn_global_load_lds(
        (const __attribute__((address_space(1))) unsigned int*)g,
        (__attribute__((address_space(3))) unsigned int*)l,
        16, 0, 0);
}

// ---------------------------------------------------------------------------
// Fused prep (R15): one kernel, block-range dispatch — saves 3 launch gaps.
//  [0,768)      : transpose Wqkv fp32 [512][1536] -> fp16 [1536][512]
//  [768,1024)   : transpose Wout fp32 [512][512]  -> fp16 [512][512]
//  [1024,9216)  : decay fp32 -> fp16 * 2^-8 (no-max softmax headroom)
//  [9216,17408) : X fp32 -> fp16 (RTN)
// ---------------------------------------------------------------------------
__global__ __launch_bounds__(256) void prep_fused_kernel(
    const float* __restrict__ Wqkv, const float* __restrict__ Wout,
    const float* __restrict__ D, const float* __restrict__ X,
    unsigned short* __restrict__ Wq, unsigned short* __restrict__ Wo,
    unsigned short* __restrict__ D16, unsigned short* __restrict__ Xf)
{
    __shared__ float T[32][33];
    const int id  = blockIdx.x;
    const int tid = threadIdx.x;

    if (id < 1024) {
        // weight transpose + fp16 cast
        const float* src;
        unsigned short* dh;
        int N, bx, by;
        if (id < 768) {
            src = Wqkv; dh = Wq; N = 1536; bx = id % 48; by = id / 48;
        } else {
            const int id2 = id - 768;
            src = Wout; dh = Wo; N = 512; bx = id2 & 15; by = id2 >> 4;
        }
        const int c = tid & 31, r0 = tid >> 5;
        const int nb = bx * 32, kb = by * 32;
        #pragma unroll
        for (int i = 0; i < 4; ++i)
            T[r0 + i * 8][c] = src[(size_t)(kb + r0 + i * 8) * N + nb + c];
        __syncthreads();
        #pragma unroll
        for (int i = 0; i < 4; ++i) {
            int n = r0 + i * 8;
            dh[(size_t)(nb + n) * GK + kb + c] = f16_bits(T[c][n]);
        }
    } else if (id < 9216) {
        // decay -> fp16 * 2^-8
        size_t i = ((size_t)(id - 1024) * 256 + tid) * 4;
        float4 v = *(const float4*)(D + i);
        ushort4 o;
        o.x = f16_bits(v.x * 0.00390625f);
        o.y = f16_bits(v.y * 0.00390625f);
        o.z = f16_bits(v.z * 0.00390625f);
        o.w = f16_bits(v.w * 0.00390625f);
        *(ushort4*)(D16 + i) = o;
    } else {
        // X -> fp16
        size_t i = ((size_t)(id - 9216) * 256 + tid) * 8;
        float4 a = *(const float4*)(X + i);
        float4 b = *(const float4*)(X + i + 4);
        float f[8] = {a.x, a.y, a.z, a.w, b.x, b.y, b.z, b.w};
        short8 o;
        #pragma unroll
        for (int e = 0; e < 8; ++e) o[e] = (short)f16_bits(f[e]);
        *(short8*)(Xf + i) = o;
    }
}

// ---------------------------------------------------------------------------
// GEMM1 (fp16 single-term): qkv = x @ W_qkv
// R12 skeleton (proven best): 2-buffer gload_lds staging, one barrier per
// K-step, XCD-chunked swizzle. [R13 counted-vmcnt: -7%; R14 no-LDS: -80% —
// LDS staging IS the coalescing mechanism, do not remove.]
// ---------------------------------------------------------------------------
__global__ __launch_bounds__(256) void gemm_qkv_mfma(
    const unsigned short* __restrict__ Xf, const unsigned short* __restrict__ Wf,
    unsigned short* __restrict__ Qf, unsigned short* __restrict__ Kf,
    unsigned short* __restrict__ Vt)
{
    __shared__ union {
        struct { unsigned short Af[2][4096], Bf[2][4096]; } s;
        unsigned short bounce[128][136];   // V-transpose bounce (epilogue only)
    } u;

    const int tid  = threadIdx.x;
    const int w    = tid >> 6;
    const int lane = tid & 63;
    const int quad = lane >> 4;
    const int l16  = lane & 15;
    // XCD-chunked swizzle: nwg = 3072 = 8 * 384; n-fastest within m-panel
    const int lb = blockIdx.x;
    const int wg = (lb & 7) * 384 + (lb >> 3);
    const int n0 = (wg % 12) * 128;
    const int m0 = (wg / 12) * 128;
    const int wm = w >> 1, wn = w & 1;

    floatx4 acc[4][4];
    #pragma unroll
    for (int im = 0; im < 4; ++im)
        #pragma unroll
        for (int in = 0; in < 4; ++in)
            acc[im][in] = (floatx4){0.f, 0.f, 0.f, 0.f};

    // prologue: stage K-tile 0 into buffer 0
    #pragma unroll
    for (int i = 0; i < 2; ++i) {
        const int row = i * 64 + w * 16 + l16;
        const size_t aoff = (size_t)(m0 + row) * GK + quad * 8;
        const size_t boff = (size_t)(n0 + row) * GK + quad * 8;
        const int lbe = (i * 4 + w) * 512;
        gload_lds16(Xf + aoff, &u.s.Af[0][lbe]);
        gload_lds16(Wf + boff, &u.s.Bf[0][lbe]);
    }

    int cur = 0;
    for (int k0 = 0; k0 < GK; k0 += 32) {
        __syncthreads();   // vmcnt(0): buf[cur] ready; lgkm: buf[cur^1] free
        if (k0 + 32 < GK) {
            const int kn = k0 + 32;
            #pragma unroll
            for (int i = 0; i < 2; ++i) {
                const int row = i * 64 + w * 16 + l16;
                const size_t aoff = (size_t)(m0 + row) * GK + kn + quad * 8;
                const size_t boff = (size_t)(n0 + row) * GK + kn + quad * 8;
                const int lbe = (i * 4 + w) * 512;
                gload_lds16(Xf + aoff, &u.s.Af[cur ^ 1][lbe]);
                gload_lds16(Wf + boff, &u.s.Bf[cur ^ 1][lbe]);
            }
        }

        half8 faf[4], fbf[4];
        #pragma unroll
        for (int t = 0; t < 4; ++t) {
            const int ca = ((wm * 4 + t) * 4 + quad) * 16 + l16;
            faf[t] = *(const half8*)&u.s.Af[cur][ca * 8];
            const int cb = ((wn * 4 + t) * 4 + quad) * 16 + l16;
            fbf[t] = *(const half8*)&u.s.Bf[cur][cb * 8];
        }
        #pragma unroll
        for (int im = 0; im < 4; ++im)
            #pragma unroll
            for (int in = 0; in < 4; ++in)
                acc[im][in] = MFMA16(faf[im], fbf[in], acc[im][in], 0, 0, 0);
        cur ^= 1;
    }

    // ---- epilogue ----
    const int which = n0 >> 9;       // 0=q 1=k 2=v (128-tiles never straddle)
    const int b    = m0 >> 10;
    const int tokb = m0 & 1023;
    if (which < 2) {
        unsigned short* OUT = which ? Kf : Qf;
        // Q: fold SCALE * log2(e) = 0.125 * 1.4426950408889634
        const float sc = which ? 1.0f : 0.18033688011112042f;
        #pragma unroll
        for (int im = 0; im < 4; ++im) {
            const int tok = tokb + wm * 64 + im * 16 + quad * 4;
            #pragma unroll
            for (int in = 0; in < 4; ++in) {
                const int ncol = n0 + wn * 64 + in * 16 + l16;
                const int h = (ncol & 511) >> 6, d = ncol & 63;
                const size_t base = ((size_t)(b * Hh + h) * Nn + tok) * DHd + d;
                #pragma unroll
                for (int r = 0; r < 4; ++r)
                    OUT[base + (size_t)r * DHd] = f16_bits(acc[im][in][r] * sc);
            }
        }
    } else {
        // V: fp16 + transpose through LDS bounce -> Vt [bh][64][1024]
        __syncthreads();
        #pragma unroll
        for (int im = 0; im < 4; ++im)
            #pragma unroll
            for (int in = 0; in < 4; ++in)
                #pragma unroll
                for (int r = 0; r < 4; ++r)
                    u.bounce[wm * 64 + im * 16 + quad * 4 + r][wn * 64 + in * 16 + l16] =
                        f16_bits(acc[im][in][r]);
        __syncthreads();
        const int c = tid >> 1, tq = (tid & 1) * 64;
        const int h = ((n0 + c) & 511) >> 6, d = c & 63;
        unsigned short* vbase = Vt + ((size_t)(b * Hh + h) * DHd + d) * Nn + tokb;
        #pragma unroll
        for (int uu = 0; uu < 8; ++uu) {
            short8 v8;
            #pragma unroll
            for (int e = 0; e < 8; ++e)
                v8[e] = (short)u.bounce[tq + uu * 8 + e][c];
            *(short8*)&vbase[tq + uu * 8] = v8;
        }
    }
}

// ---------------------------------------------------------------------------
// MFMA flash attention (R12 skeleton, unchanged): LDS double-buffer with one
// barrier per tile, 2x Q-rows per wave, no-max softmax, packed-fp16 decay,
// decay-sharing grid remap.
// ---------------------------------------------------------------------------
__global__ __launch_bounds__(256) void attn_mfma_kernel(
    const unsigned short* __restrict__ Qf, const unsigned short* __restrict__ Kf,
    const unsigned short* __restrict__ Vt, const unsigned short* __restrict__ D16,
    unsigned short* __restrict__ AOf)
{
    __shared__ unsigned short Kfs[2][32][72];   // [buf][permuted j][d]
    __shared__ unsigned short Vts[2][64][40];   // [buf][d][j]

    const int tid  = threadIdx.x;
    const int wave = tid >> 6;
    const int lane = tid & 63;
    const int quad = lane >> 4;
    const int l16  = lane & 15;
    const int lb   = blockIdx.x;                 // [0,2048)
    const int xcd  = lb & 7;
    const int r_   = lb >> 3;                    // [0,256)
    const int h    = r_ >> 5;
    const int rem  = r_ & 31;
    const int i0   = (rem >> 2) << 7;            // 8 x 128-row tiles
    const int b    = xcd * 4 + (rem & 3);
    const int bh   = b * 8 + h;
    const int iw   = i0 + wave * 32;             // this wave: rows iw..iw+31

    const size_t qoffA = ((size_t)bh * Nn + iw + l16) * DHd + quad * 8;
    const size_t qoffB = qoffA + (size_t)16 * DHd;
    const half8 qA0 = *(const half8*)(Qf + qoffA);
    const half8 qA1 = *(const half8*)(Qf + qoffA + 32);
    const half8 qB0 = *(const half8*)(Qf + qoffB);
    const half8 qB1 = *(const half8*)(Qf + qoffB + 32);

    floatx4 oA[4], oB[4];
    #pragma unroll
    for (int nt = 0; nt < 4; ++nt) {
        oA[nt] = (floatx4){0.f, 0.f, 0.f, 0.f};
        oB[nt] = (floatx4){0.f, 0.f, 0.f, 0.f};
    }
    float lA = 0.f, lB = 0.f;    // per-lane partial denominators

    const int sj  = tid >> 3, sc2 = (tid & 7) * 8;       // K tile: 32 x 64
    const int prow = ((sj >> 2) & 1) * 16 + ((sj >> 3) << 2) + (sj & 3);
    const int vd  = tid >> 2, vj8 = (tid & 3) * 8;       // Vt tile: 64 x 32
    const unsigned short* DpA = D16 + ((size_t)h * Nn + iw + l16) * Nn + quad * 8;
    const unsigned short* DpB = DpA + (size_t)16 * Nn;

    const unsigned short* kpf = Kf + (size_t)bh * Nn * DHd + (size_t)sj * DHd + sc2;
    const unsigned short* vpv = Vt + (size_t)bh * DHd * Nn + (size_t)vd * Nn + vj8;

    // prologue: tile 0 -> buf0
    short8 pk_f = *(const short8*)kpf; kpf += 32 * DHd;
    short8 pk_v = *(const short8*)vpv; vpv += 32;
    *(short8*)&Kfs[0][prow][sc2] = pk_f;
    *(short8*)&Vts[0][vd][vj8]   = pk_v;
    __syncthreads();

    int cur = 0;
    for (int j0 = 0; j0 < Nn; j0 += 32) {
        // issue next-tile loads (final iter overshoots into adjacent workspace)
        pk_f = *(const short8*)kpf; kpf += 32 * DHd;
        pk_v = *(const short8*)vpv; vpv += 32;
        const short8 dcA = *(const short8*)(DpA + j0);   // 8 fp16 decay*2^-8
        const short8 dcB = *(const short8*)(DpB + j0);

        // QK^T swapped for both q-groups
        floatx4 sA[2], sB[2];
        #pragma unroll
        for (int nh = 0; nh < 2; ++nh) {
            const int kr = nh * 16 + l16;
            half8 kf0 = *(const half8*)&Kfs[cur][kr][quad * 8];
            half8 kf1 = *(const half8*)&Kfs[cur][kr][32 + quad * 8];
            floatx4 a = (floatx4){0.f, 0.f, 0.f, 0.f};
            a = MFMA16(kf0, qA0, a, 0, 0, 0);
            a = MFMA16(kf1, qA1, a, 0, 0, 0);
            sA[nh] = a;
            floatx4 c = (floatx4){0.f, 0.f, 0.f, 0.f};
            c = MFMA16(kf0, qB0, c, 0, 0, 0);
            c = MFMA16(kf1, qB1, c, 0, 0, 0);
            sB[nh] = c;
        }

        // no-max softmax: raw exp2
        float pA[8], pB[8];
        #pragma unroll
        for (int e = 0; e < 4; ++e) {
            pA[e]     = EXP2(sA[0][e]);
            pA[4 + e] = EXP2(sA[1][e]);
            pB[e]     = EXP2(sB[0][e]);
            pB[4 + e] = EXP2(sB[1][e]);
        }
        lA += ((pA[0] + pA[1]) + (pA[2] + pA[3])) + ((pA[4] + pA[5]) + (pA[6] + pA[7]));
        lB += ((pB[0] + pB[1]) + (pB[2] + pB[3])) + ((pB[4] + pB[5]) + (pB[6] + pB[7]));

        // P * (decay*2^-8) -> fp16 A-fragments via packed fp16 multiply
        union { int i4[4]; half8 v8; } pfA, pfB;
        const int* dA = (const int*)&dcA;
        const int* dB = (const int*)&dcB;
        #pragma unroll
        for (int e = 0; e < 4; ++e) {
            fp16x2 pa = __builtin_bit_cast(fp16x2, cvt_pk_f16(pA[2 * e], pA[2 * e + 1]));
            fp16x2 da = __builtin_bit_cast(fp16x2, dA[e]);
            pfA.i4[e] = __builtin_bit_cast(int, pa * da);   // v_pk_mul_f16
            fp16x2 pb = __builtin_bit_cast(fp16x2, cvt_pk_f16(pB[2 * e], pB[2 * e + 1]));
            fp16x2 db = __builtin_bit_cast(fp16x2, dB[e]);
            pfB.i4[e] = __builtin_bit_cast(int, pb * db);
        }
        #pragma unroll
        for (int nt = 0; nt < 4; ++nt) {
            half8 vf = *(const half8*)&Vts[cur][nt * 16 + l16][quad * 8];
            oA[nt] = MFMA16(pfA.v8, vf, oA[nt], 0, 0, 0);
            oB[nt] = MFMA16(pfB.v8, vf, oB[nt], 0, 0, 0);
        }

        // write next tile into the other buffer; single barrier per tile
        *(short8*)&Kfs[cur ^ 1][prow][sc2] = pk_f;
        *(short8*)&Vts[cur ^ 1][vd][vj8]   = pk_v;
        __syncthreads();
        cur ^= 1;
    }

    // reduce per-lane partial denominators across quads (once)
    float lsA = lA;
    lsA += __shfl_xor(lsA, 16);
    lsA += __shfl_xor(lsA, 32);
    float lsB = lB;
    lsB += __shfl_xor(lsB, 16);
    lsB += __shfl_xor(lsB, 32);
    const float invA = 256.f / lsA;     // 2^8 cancels the decay pre-scale
    const float invB = 256.f / lsB;
    float irA[4], irB[4];
    #pragma unroll
    for (int r = 0; r < 4; ++r) {
        irA[r] = __shfl(invA, quad * 4 + r);
        irB[r] = __shfl(invB, quad * 4 + r);
    }
    const size_t aobA = ((size_t)b * Nn + iw) * DIMc + h * DHd;
    const size_t aobB = aobA + (size_t)16 * DIMc;
    #pragma unroll
    for (int nt = 0; nt < 4; ++nt)
        #pragma unroll
        for (int r = 0; r < 4; ++r) {
            const size_t ro = (size_t)(quad * 4 + r) * DIMc + nt * 16 + l16;
            AOf[aobA + ro] = f16_bits(oA[nt][r] * irA[r]);
            AOf[aobB + ro] = f16_bits(oB[nt][r] * irB[r]);
        }
}

// ---------------------------------------------------------------------------
// GEMM2 (fp16 single-term): out = AO @ W_out + b_out
// R12 skeleton: 2-buffer gload_lds staging + XCD-chunked swizzle (nwg = 1024).
// ---------------------------------------------------------------------------
__global__ __launch_bounds__(256) void gemm_out_mfma(
    const unsigned short* __restrict__ Af, const unsigned short* __restrict__ Wf,
    const float* __restrict__ bias, float* __restrict__ C)
{
    __shared__ struct { unsigned short Aa[2][4096], Bf[2][4096]; } s;

    const int tid  = threadIdx.x;
    const int w    = tid >> 6;
    const int lane = tid & 63;
    const int quad = lane >> 4;
    const int l16  = lane & 15;
    const int lb = blockIdx.x;
    const int wg = (lb & 7) * 128 + (lb >> 3);
    const int n0 = (wg & 3) * 128;
    const int m0 = (wg >> 2) * 128;
    const int wm = w >> 1, wn = w & 1;

    floatx4 acc[4][4];
    #pragma unroll
    for (int im = 0; im < 4; ++im)
        #pragma unroll
        for (int in = 0; in < 4; ++in)
            acc[im][in] = (floatx4){0.f, 0.f, 0.f, 0.f};

    #pragma unroll
    for (int i = 0; i < 2; ++i) {
        const int row = i * 64 + w * 16 + l16;
        const size_t aoff = (size_t)(m0 + row) * GK + quad * 8;
        const size_t boff = (size_t)(n0 + row) * GK + quad * 8;
        const int lbe = (i * 4 + w) * 512;
        gload_lds16(Af + aoff, &s.Aa[0][lbe]);
        gload_lds16(Wf + boff, &s.Bf[0][lbe]);
    }

    int cur = 0;
    for (int k0 = 0; k0 < GK; k0 += 32) {
        __syncthreads();
        if (k0 + 32 < GK) {
            const int kn = k0 + 32;
            #pragma unroll
            for (int i = 0; i < 2; ++i) {
                const int row = i * 64 + w * 16 + l16;
                const size_t aoff = (size_t)(m0 + row) * GK + kn + quad * 8;
                const size_t boff = (size_t)(n0 + row) * GK + kn + quad * 8;
                const int lbe = (i * 4 + w) * 512;
                gload_lds16(Af + aoff, &s.Aa[cur ^ 1][lbe]);
                gload_lds16(Wf + boff, &s.Bf[cur ^ 1][lbe]);
            }
        }

        half8 faf[4], fbf[4];
        #pragma unroll
        for (int t = 0; t < 4; ++t) {
            const int ca = ((wm * 4 + t) * 4 + quad) * 16 + l16;
            faf[t] = *(const half8*)&s.Aa[cur][ca * 8];
            const int cb = ((wn * 4 + t) * 4 + quad) * 16 + l16;
            fbf[t] = *(const half8*)&s.Bf[cur][cb * 8];
        }
        #pragma unroll
        for (int im = 0; im < 4; ++im)
            #pragma unroll
            for (int in = 0; in < 4; ++in)
                acc[im][in] = MFMA16(faf[im], fbf[in], acc[im][in], 0, 0, 0);
        cur ^= 1;
    }

    float biasv[4];
    #pragma unroll
    for (int in = 0; in < 4; ++in) biasv[in] = bias[n0 + wn * 64 + in * 16 + l16];
    #pragma unroll
    for (int im = 0; im < 4; ++im)
        #pragma unroll
        for (int in = 0; in < 4; ++in) {
            const int mrow = m0 + wm * 64 + im * 16 + quad * 4;
            const int ncol = n0 + wn * 64 + in * 16 + l16;
            #pragma unroll
            for (int r = 0; r < 4; ++r)
                C[(size_t)(mrow + r) * DIMc + ncol] = acc[im][in][r] + biasv[in];
        }
}

// ---------------------------------------------------------------------------
extern "C" void kernel_launch(void* const* d_in, const int* in_sizes, int n_in,
                              void* d_out, int out_size, void* d_ws, size_t ws_size,
                              hipStream_t stream)
{
    const float* x     = (const float*)d_in[0];
    const float* Wqkv  = (const float*)d_in[1];
    const float* Wout  = (const float*)d_in[2];
    const float* bout  = (const float*)d_in[3];
    const float* decay = (const float*)d_in[4];

    const size_t E = (size_t)32768 * 512;   // 16,777,216
    unsigned short* p = (unsigned short*)d_ws;
    unsigned short* Qf  = p; p += E;
    unsigned short* Kf  = p; p += E;        // attn prefetch overshoot -> Vt (ok)
    unsigned short* Vt  = p; p += E;        // attn prefetch overshoot -> AOf (ok)
    unsigned short* AOf = p; p += E;
    unsigned short* Wq  = p; p += 786432;
    unsigned short* Wo  = p; p += 262144;
    unsigned short* D16 = p;               // 8,388,608 halves
    // total: ~148 MiB. Xf ALIASES AOf (dead until attn writes AO).
    unsigned short* Xf = AOf;

    prep_fused_kernel<<<dim3(17408), 256, 0, stream>>>(Wqkv, Wout, decay, x,
                                                       Wq, Wo, D16, Xf);
    gemm_qkv_mfma<<<dim3(3072), 256, 0, stream>>>(Xf, Wq, Qf, Kf, Vt);
    attn_mfma_kernel<<<dim3(2048), 256, 0, stream>>>(Qf, Kf, Vt, D16, AOf);
    gemm_out_mfma<<<dim3(1024), 256, 0, stream>>>(AOf, Wo, bout, (float*)d_out);
}

// Round 16
// 268.198 us; speedup vs baseline: 1.5128x; 1.0747x over previous
//
#include <hip/hip_runtime.h>
#include <hip/hip_fp16.h>
#include <math.h>

// Problem constants
#define Bb 32
#define Nn 1024
#define DIMc 512
#define Hh 8
#define DHd 64
#define GK 512          // K for both projection GEMMs

typedef __attribute__((ext_vector_type(8))) short short8;     // 16B of 16-bit elems
typedef __attribute__((ext_vector_type(8))) _Float16 half8;   // MFMA f16 A/B frag
typedef __attribute__((ext_vector_type(2))) __fp16 fp16x2;    // cvt_pkrtz result
typedef __attribute__((ext_vector_type(4))) float floatx4;    // MFMA 16x16 acc

#define MFMA16 __builtin_amdgcn_mfma_f32_16x16x32_f16

#if __has_builtin(__builtin_amdgcn_exp2f)
#define EXP2(x) __builtin_amdgcn_exp2f(x)
#else
#define EXP2(x) __expf((x) * 0.6931471805599453f)
#endif

__device__ __forceinline__ unsigned short f16_bits(float f) {
    return __half_as_ushort(__float2half(f));   // RTN
}
// pack 2 fp32 -> 2 fp16 (RTZ) in one dword
__device__ __forceinline__ int cvt_pk_f16(float a, float b) {
    fp16x2 r = __builtin_amdgcn_cvt_pkrtz(a, b);
    return __builtin_bit_cast(int, r);
}

// async global->LDS, 16 bytes per lane; LDS dest = wave-uniform base + lane*16
__device__ __forceinline__ void gload_lds16(const unsigned short* g, unsigned short* l) {
    __builtin_amdgcn_global_load_lds(
        (const __attribute__((address_space(1))) unsigned int*)g,
        (__attribute__((address_space(3))) unsigned int*)l,
        16, 0, 0);
}

// ---------------------------------------------------------------------------
// Fused prep (R15): one kernel, block-range dispatch.
//  [0,768)      : transpose Wqkv fp32 [512][1536] -> fp16 [1536][512]
//  [768,1024)   : transpose Wout fp32 [512][512]  -> fp16 [512][512]
//  [1024,9216)  : decay fp32 -> fp16 * 2^-8 (no-max softmax headroom)
//  [9216,17408) : X fp32 -> fp16 (RTN)
// ---------------------------------------------------------------------------
__global__ __launch_bounds__(256) void prep_fused_kernel(
    const float* __restrict__ Wqkv, const float* __restrict__ Wout,
    const float* __restrict__ D, const float* __restrict__ X,
    unsigned short* __restrict__ Wq, unsigned short* __restrict__ Wo,
    unsigned short* __restrict__ D16, unsigned short* __restrict__ Xf)
{
    __shared__ float T[32][33];
    const int id  = blockIdx.x;
    const int tid = threadIdx.x;

    if (id < 1024) {
        const float* src;
        unsigned short* dh;
        int N, bx, by;
        if (id < 768) {
            src = Wqkv; dh = Wq; N = 1536; bx = id % 48; by = id / 48;
        } else {
            const int id2 = id - 768;
            src = Wout; dh = Wo; N = 512; bx = id2 & 15; by = id2 >> 4;
        }
        const int c = tid & 31, r0 = tid >> 5;
        const int nb = bx * 32, kb = by * 32;
        #pragma unroll
        for (int i = 0; i < 4; ++i)
            T[r0 + i * 8][c] = src[(size_t)(kb + r0 + i * 8) * N + nb + c];
        __syncthreads();
        #pragma unroll
        for (int i = 0; i < 4; ++i) {
            int n = r0 + i * 8;
            dh[(size_t)(nb + n) * GK + kb + c] = f16_bits(T[c][n]);
        }
    } else if (id < 9216) {
        size_t i = ((size_t)(id - 1024) * 256 + tid) * 4;
        float4 v = *(const float4*)(D + i);
        ushort4 o;
        o.x = f16_bits(v.x * 0.00390625f);
        o.y = f16_bits(v.y * 0.00390625f);
        o.z = f16_bits(v.z * 0.00390625f);
        o.w = f16_bits(v.w * 0.00390625f);
        *(ushort4*)(D16 + i) = o;
    } else {
        size_t i = ((size_t)(id - 9216) * 256 + tid) * 8;
        float4 a = *(const float4*)(X + i);
        float4 b = *(const float4*)(X + i + 4);
        float f[8] = {a.x, a.y, a.z, a.w, b.x, b.y, b.z, b.w};
        short8 o;
        #pragma unroll
        for (int e = 0; e < 8; ++e) o[e] = (short)f16_bits(f[e]);
        *(short8*)(Xf + i) = o;
    }
}

// ---------------------------------------------------------------------------
// GEMM1 (fp16 single-term): qkv = x @ W_qkv
// R16: 256x128 tile @ 512 threads (8 waves, per-wave 64x64 = same inner
// loop), 2-phase gload_lds skeleton UNCHANGED. LDS 48KB + ~80 VGPR ->
// 3 blocks x 8 waves = 24 waves/CU (was ~9.6): occupancy is the lever in
// the sync-bound regime (m114: wave overlap carries the 2-phase structure).
// LDS store group (i*8+w) <-> read group (wm*4+t) bijective over 16x16-row
// groups; B staged in 1 issue (8 waves x 16 rows = 128).
// ---------------------------------------------------------------------------
__global__ __launch_bounds__(512) void gemm_qkv_mfma(
    const unsigned short* __restrict__ Xf, const unsigned short* __restrict__ Wf,
    unsigned short* __restrict__ Qf, unsigned short* __restrict__ Kf,
    unsigned short* __restrict__ Vt)
{
    __shared__ union {
        struct { unsigned short Af[2][8192], Bf[2][4096]; } s;   // 48 KB
        unsigned short bounce[128][136];   // V-transpose (epilogue, half-tile)
    } u;

    const int tid  = threadIdx.x;
    const int w    = tid >> 6;            // 0..7
    const int lane = tid & 63;
    const int quad = lane >> 4;
    const int l16  = lane & 15;
    // XCD-chunked swizzle: nwg = 1536 = 8 * 192; n-fastest within m-panel
    const int lb = blockIdx.x;
    const int wg = (lb & 7) * 192 + (lb >> 3);
    const int n0 = (wg % 12) * 128;
    const int m0 = (wg / 12) * 256;
    const int wm = w >> 1, wn = w & 1;    // wm 0..3 (64-row band), wn 0..1

    floatx4 acc[4][4];
    #pragma unroll
    for (int im = 0; im < 4; ++im)
        #pragma unroll
        for (int in = 0; in < 4; ++in)
            acc[im][in] = (floatx4){0.f, 0.f, 0.f, 0.f};

    // prologue: stage K-tile 0 into buffer 0 (A: 2 issues of 128 rows; B: 1)
    #pragma unroll
    for (int i = 0; i < 2; ++i) {
        const int row = i * 128 + w * 16 + l16;
        gload_lds16(Xf + (size_t)(m0 + row) * GK + quad * 8,
                    &u.s.Af[0][(i * 8 + w) * 512]);
    }
    gload_lds16(Wf + (size_t)(n0 + w * 16 + l16) * GK + quad * 8,
                &u.s.Bf[0][w * 512]);

    int cur = 0;
    for (int k0 = 0; k0 < GK; k0 += 32) {
        __syncthreads();   // vmcnt(0): buf[cur] ready; lgkm: buf[cur^1] free
        if (k0 + 32 < GK) {
            const int kn = k0 + 32;
            #pragma unroll
            for (int i = 0; i < 2; ++i) {
                const int row = i * 128 + w * 16 + l16;
                gload_lds16(Xf + (size_t)(m0 + row) * GK + kn + quad * 8,
                            &u.s.Af[cur ^ 1][(i * 8 + w) * 512]);
            }
            gload_lds16(Wf + (size_t)(n0 + w * 16 + l16) * GK + kn + quad * 8,
                        &u.s.Bf[cur ^ 1][w * 512]);
        }

        half8 faf[4], fbf[4];
        #pragma unroll
        for (int t = 0; t < 4; ++t) {
            const int ca = ((wm * 4 + t) * 4 + quad) * 16 + l16;   // 16 groups
            faf[t] = *(const half8*)&u.s.Af[cur][ca * 8];
            const int cb = ((wn * 4 + t) * 4 + quad) * 16 + l16;   // 8 groups
            fbf[t] = *(const half8*)&u.s.Bf[cur][cb * 8];
        }
        #pragma unroll
        for (int im = 0; im < 4; ++im)
            #pragma unroll
            for (int in = 0; in < 4; ++in)
                acc[im][in] = MFMA16(faf[im], fbf[in], acc[im][in], 0, 0, 0);
        cur ^= 1;
    }

    // ---- epilogue ----
    const int which = n0 >> 9;       // 0=q 1=k 2=v (128-col tiles never straddle)
    const int b    = m0 >> 10;       // 256-row tiles never straddle a batch
    const int tokb = m0 & 1023;
    if (which < 2) {
        unsigned short* OUT = which ? Kf : Qf;
        // Q: fold SCALE * log2(e) = 0.125 * 1.4426950408889634
        const float sc = which ? 1.0f : 0.18033688011112042f;
        #pragma unroll
        for (int im = 0; im < 4; ++im) {
            const int tok = tokb + wm * 64 + im * 16 + quad * 4;
            #pragma unroll
            for (int in = 0; in < 4; ++in) {
                const int ncol = n0 + wn * 64 + in * 16 + l16;
                const int h = (ncol & 511) >> 6, d = ncol & 63;
                const size_t base = ((size_t)(b * Hh + h) * Nn + tok) * DHd + d;
                #pragma unroll
                for (int r = 0; r < 4; ++r)
                    OUT[base + (size_t)r * DHd] = f16_bits(acc[im][in][r] * sc);
            }
        }
    } else {
        // V: fp16 + transpose in two 128-row halves through the LDS bounce
        __syncthreads();             // staging reads complete before union reuse
        #pragma unroll
        for (int half = 0; half < 2; ++half) {
            if ((wm >> 1) == half) {
                const int br = (wm & 1) * 64;
                #pragma unroll
                for (int im = 0; im < 4; ++im)
                    #pragma unroll
                    for (int in = 0; in < 4; ++in)
                        #pragma unroll
                        for (int r = 0; r < 4; ++r)
                            u.bounce[br + im * 16 + quad * 4 + r][wn * 64 + in * 16 + l16] =
                                f16_bits(acc[im][in][r]);
            }
            __syncthreads();
            const int c = tid >> 2, tq = (tid & 3) * 32;
            const int h = ((n0 + c) & 511) >> 6, d = c & 63;
            unsigned short* vbase = Vt + ((size_t)(b * Hh + h) * DHd + d) * Nn
                                       + tokb + half * 128;
            #pragma unroll
            for (int uu = 0; uu < 4; ++uu) {
                short8 v8;
                #pragma unroll
                for (int e = 0; e < 8; ++e)
                    v8[e] = (short)u.bounce[tq + uu * 8 + e][c];
                *(short8*)&vbase[tq + uu * 8] = v8;
            }
            __syncthreads();         // before next half overwrites the bounce
        }
    }
}

// ---------------------------------------------------------------------------
// MFMA flash attention (R12 skeleton, unchanged): LDS double-buffer with one
// barrier per tile, 2x Q-rows per wave, no-max softmax, packed-fp16 decay,
// decay-sharing grid remap.
// ---------------------------------------------------------------------------
__global__ __launch_bounds__(256) void attn_mfma_kernel(
    const unsigned short* __restrict__ Qf, const unsigned short* __restrict__ Kf,
    const unsigned short* __restrict__ Vt, const unsigned short* __restrict__ D16,
    unsigned short* __restrict__ AOf)
{
    __shared__ unsigned short Kfs[2][32][72];   // [buf][permuted j][d]
    __shared__ unsigned short Vts[2][64][40];   // [buf][d][j]

    const int tid  = threadIdx.x;
    const int wave = tid >> 6;
    const int lane = tid & 63;
    const int quad = lane >> 4;
    const int l16  = lane & 15;
    const int lb   = blockIdx.x;                 // [0,2048)
    const int xcd  = lb & 7;
    const int r_   = lb >> 3;                    // [0,256)
    const int h    = r_ >> 5;
    const int rem  = r_ & 31;
    const int i0   = (rem >> 2) << 7;            // 8 x 128-row tiles
    const int b    = xcd * 4 + (rem & 3);
    const int bh   = b * 8 + h;
    const int iw   = i0 + wave * 32;             // this wave: rows iw..iw+31

    const size_t qoffA = ((size_t)bh * Nn + iw + l16) * DHd + quad * 8;
    const size_t qoffB = qoffA + (size_t)16 * DHd;
    const half8 qA0 = *(const half8*)(Qf + qoffA);
    const half8 qA1 = *(const half8*)(Qf + qoffA + 32);
    const half8 qB0 = *(const half8*)(Qf + qoffB);
    const half8 qB1 = *(const half8*)(Qf + qoffB + 32);

    floatx4 oA[4], oB[4];
    #pragma unroll
    for (int nt = 0; nt < 4; ++nt) {
        oA[nt] = (floatx4){0.f, 0.f, 0.f, 0.f};
        oB[nt] = (floatx4){0.f, 0.f, 0.f, 0.f};
    }
    float lA = 0.f, lB = 0.f;    // per-lane partial denominators

    const int sj  = tid >> 3, sc2 = (tid & 7) * 8;       // K tile: 32 x 64
    const int prow = ((sj >> 2) & 1) * 16 + ((sj >> 3) << 2) + (sj & 3);
    const int vd  = tid >> 2, vj8 = (tid & 3) * 8;       // Vt tile: 64 x 32
    const unsigned short* DpA = D16 + ((size_t)h * Nn + iw + l16) * Nn + quad * 8;
    const unsigned short* DpB = DpA + (size_t)16 * Nn;

    const unsigned short* kpf = Kf + (size_t)bh * Nn * DHd + (size_t)sj * DHd + sc2;
    const unsigned short* vpv = Vt + (size_t)bh * DHd * Nn + (size_t)vd * Nn + vj8;

    // prologue: tile 0 -> buf0
    short8 pk_f = *(const short8*)kpf; kpf += 32 * DHd;
    short8 pk_v = *(const short8*)vpv; vpv += 32;
    *(short8*)&Kfs[0][prow][sc2] = pk_f;
    *(short8*)&Vts[0][vd][vj8]   = pk_v;
    __syncthreads();

    int cur = 0;
    for (int j0 = 0; j0 < Nn; j0 += 32) {
        // issue next-tile loads (final iter overshoots into adjacent workspace)
        pk_f = *(const short8*)kpf; kpf += 32 * DHd;
        pk_v = *(const short8*)vpv; vpv += 32;
        const short8 dcA = *(const short8*)(DpA + j0);   // 8 fp16 decay*2^-8
        const short8 dcB = *(const short8*)(DpB + j0);

        // QK^T swapped for both q-groups
        floatx4 sA[2], sB[2];
        #pragma unroll
        for (int nh = 0; nh < 2; ++nh) {
            const int kr = nh * 16 + l16;
            half8 kf0 = *(const half8*)&Kfs[cur][kr][quad * 8];
            half8 kf1 = *(const half8*)&Kfs[cur][kr][32 + quad * 8];
            floatx4 a = (floatx4){0.f, 0.f, 0.f, 0.f};
            a = MFMA16(kf0, qA0, a, 0, 0, 0);
            a = MFMA16(kf1, qA1, a, 0, 0, 0);
            sA[nh] = a;
            floatx4 c = (floatx4){0.f, 0.f, 0.f, 0.f};
            c = MFMA16(kf0, qB0, c, 0, 0, 0);
            c = MFMA16(kf1, qB1, c, 0, 0, 0);
            sB[nh] = c;
        }

        // no-max softmax: raw exp2
        float pA[8], pB[8];
        #pragma unroll
        for (int e = 0; e < 4; ++e) {
            pA[e]     = EXP2(sA[0][e]);
            pA[4 + e] = EXP2(sA[1][e]);
            pB[e]     = EXP2(sB[0][e]);
            pB[4 + e] = EXP2(sB[1][e]);
        }
        lA += ((pA[0] + pA[1]) + (pA[2] + pA[3])) + ((pA[4] + pA[5]) + (pA[6] + pA[7]));
        lB += ((pB[0] + pB[1]) + (pB[2] + pB[3])) + ((pB[4] + pB[5]) + (pB[6] + pB[7]));

        // P * (decay*2^-8) -> fp16 A-fragments via packed fp16 multiply
        union { int i4[4]; half8 v8; } pfA, pfB;
        const int* dA = (const int*)&dcA;
        const int* dB = (const int*)&dcB;
        #pragma unroll
        for (int e = 0; e < 4; ++e) {
            fp16x2 pa = __builtin_bit_cast(fp16x2, cvt_pk_f16(pA[2 * e], pA[2 * e + 1]));
            fp16x2 da = __builtin_bit_cast(fp16x2, dA[e]);
            pfA.i4[e] = __builtin_bit_cast(int, pa * da);   // v_pk_mul_f16
            fp16x2 pb = __builtin_bit_cast(fp16x2, cvt_pk_f16(pB[2 * e], pB[2 * e + 1]));
            fp16x2 db = __builtin_bit_cast(fp16x2, dB[e]);
            pfB.i4[e] = __builtin_bit_cast(int, pb * db);
        }
        #pragma unroll
        for (int nt = 0; nt < 4; ++nt) {
            half8 vf = *(const half8*)&Vts[cur][nt * 16 + l16][quad * 8];
            oA[nt] = MFMA16(pfA.v8, vf, oA[nt], 0, 0, 0);
            oB[nt] = MFMA16(pfB.v8, vf, oB[nt], 0, 0, 0);
        }

        // write next tile into the other buffer; single barrier per tile
        *(short8*)&Kfs[cur ^ 1][prow][sc2] = pk_f;
        *(short8*)&Vts[cur ^ 1][vd][vj8]   = pk_v;
        __syncthreads();
        cur ^= 1;
    }

    // reduce per-lane partial denominators across quads (once)
    float lsA = lA;
    lsA += __shfl_xor(lsA, 16);
    lsA += __shfl_xor(lsA, 32);
    float lsB = lB;
    lsB += __shfl_xor(lsB, 16);
    lsB += __shfl_xor(lsB, 32);
    const float invA = 256.f / lsA;     // 2^8 cancels the decay pre-scale
    const float invB = 256.f / lsB;
    float irA[4], irB[4];
    #pragma unroll
    for (int r = 0; r < 4; ++r) {
        irA[r] = __shfl(invA, quad * 4 + r);
        irB[r] = __shfl(invB, quad * 4 + r);
    }
    const size_t aobA = ((size_t)b * Nn + iw) * DIMc + h * DHd;
    const size_t aobB = aobA + (size_t)16 * DIMc;
    #pragma unroll
    for (int nt = 0; nt < 4; ++nt)
        #pragma unroll
        for (int r = 0; r < 4; ++r) {
            const size_t ro = (size_t)(quad * 4 + r) * DIMc + nt * 16 + l16;
            AOf[aobA + ro] = f16_bits(oA[nt][r] * irA[r]);
            AOf[aobB + ro] = f16_bits(oB[nt][r] * irB[r]);
        }
}

// ---------------------------------------------------------------------------
// GEMM2 (fp16 single-term): out = AO @ W_out + b_out
// R16: 256x128 tile @ 512 threads, same 2-phase skeleton; nwg = 512 = 8*64.
// ---------------------------------------------------------------------------
__global__ __launch_bounds__(512) void gemm_out_mfma(
    const unsigned short* __restrict__ Af, const unsigned short* __restrict__ Wf,
    const float* __restrict__ bias, float* __restrict__ C)
{
    __shared__ struct { unsigned short Aa[2][8192], Bf[2][4096]; } s;   // 48 KB

    const int tid  = threadIdx.x;
    const int w    = tid >> 6;
    const int lane = tid & 63;
    const int quad = lane >> 4;
    const int l16  = lane & 15;
    const int lb = blockIdx.x;
    const int wg = (lb & 7) * 64 + (lb >> 3);
    const int n0 = (wg & 3) * 128;
    const int m0 = (wg >> 2) * 256;
    const int wm = w >> 1, wn = w & 1;

    floatx4 acc[4][4];
    #pragma unroll
    for (int im = 0; im < 4; ++im)
        #pragma unroll
        for (int in = 0; in < 4; ++in)
            acc[im][in] = (floatx4){0.f, 0.f, 0.f, 0.f};

    #pragma unroll
    for (int i = 0; i < 2; ++i) {
        const int row = i * 128 + w * 16 + l16;
        gload_lds16(Af + (size_t)(m0 + row) * GK + quad * 8,
                    &s.Aa[0][(i * 8 + w) * 512]);
    }
    gload_lds16(Wf + (size_t)(n0 + w * 16 + l16) * GK + quad * 8,
                &s.Bf[0][w * 512]);

    int cur = 0;
    for (int k0 = 0; k0 < GK; k0 += 32) {
        __syncthreads();
        if (k0 + 32 < GK) {
            const int kn = k0 + 32;
            #pragma unroll
            for (int i = 0; i < 2; ++i) {
                const int row = i * 128 + w * 16 + l16;
                gload_lds16(Af + (size_t)(m0 + row) * GK + kn + quad * 8,
                            &s.Aa[cur ^ 1][(i * 8 + w) * 512]);
            }
            gload_lds16(Wf + (size_t)(n0 + w * 16 + l16) * GK + kn + quad * 8,
                        &s.Bf[cur ^ 1][w * 512]);
        }

        half8 faf[4], fbf[4];
        #pragma unroll
        for (int t = 0; t < 4; ++t) {
            const int ca = ((wm * 4 + t) * 4 + quad) * 16 + l16;
            faf[t] = *(const half8*)&s.Aa[cur][ca * 8];
            const int cb = ((wn * 4 + t) * 4 + quad) * 16 + l16;
            fbf[t] = *(const half8*)&s.Bf[cur][cb * 8];
        }
        #pragma unroll
        for (int im = 0; im < 4; ++im)
            #pragma unroll
            for (int in = 0; in < 4; ++in)
                acc[im][in] = MFMA16(faf[im], fbf[in], acc[im][in], 0, 0, 0);
        cur ^= 1;
    }

    float biasv[4];
    #pragma unroll
    for (int in = 0; in < 4; ++in) biasv[in] = bias[n0 + wn * 64 + in * 16 + l16];
    #pragma unroll
    for (int im = 0; im < 4; ++im)
        #pragma unroll
        for (int in = 0; in < 4; ++in) {
            const int mrow = m0 + wm * 64 + im * 16 + quad * 4;
            const int ncol = n0 + wn * 64 + in * 16 + l16;
            #pragma unroll
            for (int r = 0; r < 4; ++r)
                C[(size_t)(mrow + r) * DIMc + ncol] = acc[im][in][r] + biasv[in];
        }
}

// ---------------------------------------------------------------------------
extern "C" void kernel_launch(void* const* d_in, const int* in_sizes, int n_in,
                              void* d_out, int out_size, void* d_ws, size_t ws_size,
                              hipStream_t stream)
{
    const float* x     = (const float*)d_in[0];
    const float* Wqkv  = (const float*)d_in[1];
    const float* Wout  = (const float*)d_in[2];
    const float* bout  = (const float*)d_in[3];
    const float* decay = (const float*)d_in[4];

    const size_t E = (size_t)32768 * 512;   // 16,777,216
    unsigned short* p = (unsigned short*)d_ws;
    unsigned short* Qf  = p; p += E;
    unsigned short* Kf  = p; p += E;        // attn prefetch overshoot -> Vt (ok)
    unsigned short* Vt  = p; p += E;        // attn prefetch overshoot -> AOf (ok)
    unsigned short* AOf = p; p += E;
    unsigned short* Wq  = p; p += 786432;
    unsigned short* Wo  = p; p += 262144;
    unsigned short* D16 = p;               // 8,388,608 halves
    // total: ~148 MiB. Xf ALIASES AOf (dead until attn writes AO).
    unsigned short* Xf = AOf;

    prep_fused_kernel<<<dim3(17408), 256, 0, stream>>>(Wqkv, Wout, decay, x,
                                                       Wq, Wo, D16, Xf);
    gemm_qkv_mfma<<<dim3(1536), 512, 0, stream>>>(Xf, Wq, Qf, Kf, Vt);
    attn_mfma_kernel<<<dim3(2048), 256, 0, stream>>>(Qf, Kf, Vt, D16, AOf);
    gemm_out_mfma<<<dim3(512), 512, 0, stream>>>(AOf, Wo, bout, (float*)d_out);
}